// Round 1
// baseline (892.469 us; speedup 1.0000x reference)
//
#include <hip/hip_runtime.h>
#include <cstdint>
#include <cstddef>

#define TOKENS 32768
#define DOUT 1024

typedef __attribute__((ext_vector_type(8))) short short8;
typedef __attribute__((ext_vector_type(4))) float f32x4;

// fp32 -> bf16 bits, round-nearest-even (inputs are finite)
__device__ __forceinline__ short f2bf(float x) {
    unsigned u = __builtin_bit_cast(unsigned, x);
    u = (u + 0x7FFFu + ((u >> 16) & 1u)) >> 16;
    return (short)u;
}

// ---- kernel 1: bucket token positions by category --------------------------
__global__ void compact_kernel(const int* __restrict__ tok_ids,
                               const int* __restrict__ cat_table,
                               int* __restrict__ counts,
                               int* __restrict__ lists) {
    int i = blockIdx.x * 256 + threadIdx.x;           // 0..32767
    int tok = tok_ids[i];
    int c = cat_table[tok];
    int pos = atomicAdd(&counts[c], 1);
    lists[c * TOKENS + pos] = (int)(((unsigned)tok << 15) | (unsigned)i);
}

// ---- kernel 2: W[K][1024] fp32 -> Wt[1024][K] bf16 -------------------------
__global__ void transpose_kernel(const float* __restrict__ W,
                                 short* __restrict__ Wt, int K) {
    __shared__ short tile[32][33];
    int k0 = blockIdx.x * 32, n0 = blockIdx.y * 32;
    int t = threadIdx.x;                               // 256 threads
    int nl = t & 31, g = t >> 5;                       // g: 0..7
#pragma unroll
    for (int e = 0; e < 4; ++e) {
        int k = g * 4 + e;
        tile[k][nl] = f2bf(W[(size_t)(k0 + k) * DOUT + n0 + nl]);
    }
    __syncthreads();
    int kl = t & 31;
#pragma unroll
    for (int e = 0; e < 4; ++e) {
        int n = g * 4 + e;
        Wt[(size_t)(n0 + n) * K + k0 + kl] = tile[kl][n];
    }
}

// ---- kernel 3: per-category gathered GEMM ----------------------------------
// out[pos, 0:1024] = bf16(emb[tok, 0:K]) @ bf16(W[0:K, 0:1024]) + b
// 128x128 tile, 4 waves, each wave 64x64 via 4x4 mfma_f32_16x16x32_bf16.
template <bool USE_WT>
__global__ __launch_bounds__(256)
void gemm_kernel(const float* __restrict__ emb,
                 const float* __restrict__ W,
                 const short* __restrict__ Wt,
                 const float* __restrict__ bias,
                 const int* __restrict__ list,
                 const int* __restrict__ count_p,
                 float* __restrict__ out, int K) {
    __shared__ short lds_A[128 * 40];   // row r at r*40 (stride pad: 2-way max)
    __shared__ short lds_B[128 * 40];   // row n at n*40, holds B^T chunk [n][k]
    __shared__ int   row_tok[128];
    __shared__ int   row_dst[128];

    const int count = *count_p;
    const int m0 = blockIdx.x * 128;
    if (m0 >= count) return;
    const int valid = min(128, count - m0);
    const int n0 = blockIdx.y * 128;

    const int t = threadIdx.x;
    if (t < 128) {
        if (t < valid) {
            unsigned pack = (unsigned)list[m0 + t];
            row_tok[t] = (int)(pack >> 15);
            row_dst[t] = (int)(pack & 32767u);
        } else {
            row_tok[t] = 0;
            row_dst[t] = -1;
        }
    }
    __syncthreads();

    const int w = t >> 6, L = t & 63;
    const int quad = L >> 4, l16 = L & 15;
    const int m_off = (w & 1) * 64;
    const int n_off = (w >> 1) * 64;

    f32x4 acc[4][4];
#pragma unroll
    for (int i = 0; i < 4; ++i)
#pragma unroll
        for (int j = 0; j < 4; ++j) acc[i][j] = (f32x4)0.0f;

    // A staging map: thread t -> row ar (0..127), 16-col group acg (0 or 16)
    const int ar = t >> 1, acg = (t & 1) * 16;
    const size_t arow = (size_t)row_tok[ar] * (size_t)K;

    for (int k0 = 0; k0 < K; k0 += 32) {
        // ---- stage A: 128 rows x 32 k, fp32 gather -> bf16 LDS
        {
            const float4* src =
                reinterpret_cast<const float4*>(emb + arow + k0 + acg);
            float4 f0 = src[0], f1 = src[1], f2 = src[2], f3 = src[3];
            short8 s0, s1;
            s0[0] = f2bf(f0.x); s0[1] = f2bf(f0.y); s0[2] = f2bf(f0.z); s0[3] = f2bf(f0.w);
            s0[4] = f2bf(f1.x); s0[5] = f2bf(f1.y); s0[6] = f2bf(f1.z); s0[7] = f2bf(f1.w);
            s1[0] = f2bf(f2.x); s1[1] = f2bf(f2.y); s1[2] = f2bf(f2.z); s1[3] = f2bf(f2.w);
            s1[4] = f2bf(f3.x); s1[5] = f2bf(f3.y); s1[6] = f2bf(f3.z); s1[7] = f2bf(f3.w);
            *(short8*)&lds_A[ar * 40 + acg]     = s0;
            *(short8*)&lds_A[ar * 40 + acg + 8] = s1;
        }
        // ---- stage B: 32 k x 128 n, transposed into lds_B[n][k]
        if (USE_WT) {
            const int bn = t >> 1, bh = (t & 1) * 16;
            const short8* src = reinterpret_cast<const short8*>(
                Wt + (size_t)(n0 + bn) * (size_t)K + k0 + bh);
            short8 v0 = src[0], v1 = src[1];
            *(short8*)&lds_B[bn * 40 + bh]     = v0;
            *(short8*)&lds_B[bn * 40 + bh + 8] = v1;
        } else {
            const int bk = t >> 3, bq = (t & 7) * 4;
#pragma unroll
            for (int q = 0; q < 4; ++q) {
                int nb = bq + q * 32;
                float4 f = *reinterpret_cast<const float4*>(
                    W + (size_t)(k0 + bk) * DOUT + n0 + nb);
                lds_B[(nb + 0) * 40 + bk] = f2bf(f.x);
                lds_B[(nb + 1) * 40 + bk] = f2bf(f.y);
                lds_B[(nb + 2) * 40 + bk] = f2bf(f.z);
                lds_B[(nb + 3) * 40 + bk] = f2bf(f.w);
            }
        }
        __syncthreads();

        // ---- fragments + MFMA
        short8 af[4], bf[4];
#pragma unroll
        for (int mi = 0; mi < 4; ++mi)
            af[mi] = *(const short8*)&lds_A[(m_off + mi * 16 + l16) * 40 + quad * 8];
#pragma unroll
        for (int ni = 0; ni < 4; ++ni)
            bf[ni] = *(const short8*)&lds_B[(n_off + ni * 16 + l16) * 40 + quad * 8];
#pragma unroll
        for (int mi = 0; mi < 4; ++mi)
#pragma unroll
            for (int ni = 0; ni < 4; ++ni)
                acc[mi][ni] = __builtin_amdgcn_mfma_f32_16x16x32_bf16(
                    af[mi], bf[ni], acc[mi][ni], 0, 0, 0);
        __syncthreads();
    }

    // ---- epilogue: bias + scatter rows to their token positions
    float bv[4];
#pragma unroll
    for (int ni = 0; ni < 4; ++ni) bv[ni] = bias[n0 + n_off + ni * 16 + l16];

#pragma unroll
    for (int mi = 0; mi < 4; ++mi) {
        int mb = m_off + mi * 16 + quad * 4;
#pragma unroll
        for (int r = 0; r < 4; ++r) {
            int m = mb + r;
            if (m < valid) {
                size_t dst = (size_t)row_dst[m] * DOUT;
#pragma unroll
                for (int ni = 0; ni < 4; ++ni)
                    out[dst + n0 + n_off + ni * 16 + l16] = acc[mi][ni][r] + bv[ni];
            }
        }
    }
}

// ---------------------------------------------------------------------------
extern "C" void kernel_launch(void* const* d_in, const int* in_sizes, int n_in,
                              void* d_out, int out_size, void* d_ws, size_t ws_size,
                              hipStream_t stream) {
    const int* token_ids = (const int*)d_in[0];
    const int* cat_table = (const int*)d_in[1];
    const float* emb[4] = {(const float*)d_in[2], (const float*)d_in[5],
                           (const float*)d_in[8], (const float*)d_in[11]};
    const float* Wm[4]  = {(const float*)d_in[3], (const float*)d_in[6],
                           (const float*)d_in[9], (const float*)d_in[12]};
    const float* bm[4]  = {(const float*)d_in[4], (const float*)d_in[7],
                           (const float*)d_in[10], (const float*)d_in[13]};
    const int Ks[4] = {1536, 1024, 512, 256};
    float* out = (float*)d_out;

    // workspace layout
    char* ws = (char*)d_ws;
    int* counts = (int*)ws;                       // 4 ints
    int* lists = (int*)(ws + 16);                 // 4 * 32768 ints
    size_t wt_off = (16 + (size_t)4 * TOKENS * 4 + 255) & ~(size_t)255;
    short* wt[4];
    size_t o = wt_off;
    for (int c = 0; c < 4; ++c) {
        wt[c] = (short*)(ws + o);
        o += (size_t)DOUT * Ks[c] * sizeof(short);
    }
    const bool use_wt = (ws_size >= o);

    hipMemsetAsync(counts, 0, 16, stream);
    compact_kernel<<<TOKENS / 256, 256, 0, stream>>>(token_ids, cat_table,
                                                     counts, lists);
    if (use_wt) {
        for (int c = 0; c < 4; ++c)
            transpose_kernel<<<dim3(Ks[c] / 32, DOUT / 32), 256, 0, stream>>>(
                Wm[c], wt[c], Ks[c]);
    }
    dim3 grid(TOKENS / 128, DOUT / 128);
    for (int c = 0; c < 4; ++c) {
        if (use_wt)
            gemm_kernel<true><<<grid, 256, 0, stream>>>(
                emb[c], Wm[c], wt[c], bm[c], lists + c * TOKENS, counts + c,
                out, Ks[c]);
        else
            gemm_kernel<false><<<grid, 256, 0, stream>>>(
                emb[c], Wm[c], wt[c], bm[c], lists + c * TOKENS, counts + c,
                out, Ks[c]);
    }
}

// Round 2
// 891.399 us; speedup vs baseline: 1.0012x; 1.0012x over previous
//
#include <hip/hip_runtime.h>
#include <cstdint>
#include <cstddef>

#define TOKENS 32768
#define DOUT 1024

typedef __attribute__((ext_vector_type(8))) short short8;
typedef __attribute__((ext_vector_type(4))) float f32x4;

__device__ __constant__ const int KS[4] = {1536, 1024, 512, 256};
// arena offsets in shorts
__device__ __constant__ const size_t OFFA[4] = {
    0, (size_t)TOKENS * 1536, (size_t)TOKENS * 2560, (size_t)TOKENS * 3072};
__device__ __constant__ const size_t OFFB[4] = {
    0, (size_t)DOUT * 1536, (size_t)DOUT * 2560, (size_t)DOUT * 3072};

#define GLDS16(g, l)                                                        \
    __builtin_amdgcn_global_load_lds(                                       \
        (const __attribute__((address_space(1))) void*)(g),                 \
        (__attribute__((address_space(3))) void*)(l), 16, 0, 0)

// fp32 -> bf16 bits, round-nearest-even (inputs are finite)
__device__ __forceinline__ short f2bf(float x) {
    unsigned u = __builtin_bit_cast(unsigned, x);
    u = (u + 0x7FFFu + ((u >> 16) & 1u)) >> 16;
    return (short)u;
}

// ---- kernel 1: bucket token positions by category --------------------------
__global__ void compact_kernel(const int* __restrict__ tok_ids,
                               const int* __restrict__ cat_table,
                               int* __restrict__ counts,
                               int* __restrict__ lists) {
    int i = blockIdx.x * 256 + threadIdx.x;
    int tok = tok_ids[i];
    int c = cat_table[tok];
    int pos = atomicAdd(&counts[c], 1);
    lists[c * TOKENS + pos] = (int)(((unsigned)tok << 15) | (unsigned)i);
}

// ---- kernel 2: W[K][1024] fp32 -> bf16 panel layout ------------------------
// Wt element (n, k) at OFFB[cat] + ((n>>7)*(K>>5) + (k>>5))*4096
//                              + ((k>>3)&3)*1024 + (n&127)*8 + (k&7)
__global__ __launch_bounds__(256) void conv_w_kernel(
    const float* __restrict__ W0, const float* __restrict__ W1,
    const float* __restrict__ W2, const float* __restrict__ W3,
    short* __restrict__ Wt_arena) {
    int p = blockIdx.x;  // flattened k-panel over cats: {48,32,16,8} -> 104
    int cat, panel;
    if (p < 48)      { cat = 0; panel = p; }
    else if (p < 80) { cat = 1; panel = p - 48; }
    else if (p < 96) { cat = 2; panel = p - 80; }
    else             { cat = 3; panel = p - 96; }
    const float* W = cat == 0 ? W0 : cat == 1 ? W1 : cat == 2 ? W2 : W3;
    const int K = KS[cat];
    const int nt = blockIdx.y;
    short* dst = Wt_arena + OFFB[cat] +
                 ((size_t)nt * (size_t)(K >> 5) + panel) * 4096;
    for (int ch = threadIdx.x; ch < 512; ch += 256) {
        int quad = ch >> 7, n = ch & 127;
        int kb = panel * 32 + quad * 8;
        const float* src = W + (size_t)kb * DOUT + nt * 128 + n;
        short8 s;
#pragma unroll
        for (int j = 0; j < 8; ++j) s[j] = f2bf(src[(size_t)j * DOUT]);
        *(short8*)(dst + quad * 1024 + n * 8) = s;
    }
}

// ---- kernel 3: gather emb rows -> compact bf16 A in panel layout -----------
// A element (row r, k) at OFFA[cat] + ((r>>7)*(K>>5) + (k>>5))*4096
//                              + ((k>>3)&3)*1024 + (r&127)*8 + (k&7)
__global__ __launch_bounds__(256) void gather_a_kernel(
    const float* __restrict__ e0, const float* __restrict__ e1,
    const float* __restrict__ e2, const float* __restrict__ e3,
    short* __restrict__ A_arena, const int* __restrict__ lists,
    const int* __restrict__ counts) {
    const int cat = blockIdx.y;
    const float* emb = cat == 0 ? e0 : cat == 1 ? e1 : cat == 2 ? e2 : e3;
    const int K = KS[cat];
    short* A = A_arena + OFFA[cat];
    const int count = counts[cat];
    const int w = threadIdx.x >> 6, L = threadIdx.x & 63;
    const int groups = (count + 3) >> 2;
    for (int g = blockIdx.x * 4 + w; g < groups; g += gridDim.x * 4) {
        int row = g * 4 + (L & 3);
        int tok = 0;
        if (row < count) tok = (int)(((unsigned)lists[cat * TOKENS + row]) >> 15);
        const float* src = emb + (size_t)tok * (size_t)K;
        short* dstrow = A + (size_t)(row >> 7) * (size_t)(K >> 5) * 4096 +
                        (row & 127) * 8;
        for (int k = (L >> 2) * 8; k < K; k += 128) {
            float4 f0 = *(const float4*)(src + k);
            float4 f1 = *(const float4*)(src + k + 4);
            short8 s;
            s[0] = f2bf(f0.x); s[1] = f2bf(f0.y);
            s[2] = f2bf(f0.z); s[3] = f2bf(f0.w);
            s[4] = f2bf(f1.x); s[5] = f2bf(f1.y);
            s[6] = f2bf(f1.z); s[7] = f2bf(f1.w);
            *(short8*)(dstrow + (size_t)(k >> 5) * 4096 + ((k >> 3) & 3) * 1024) = s;
        }
    }
}

// ---- kernel 4: fused all-category GEMM -------------------------------------
// out[dst, n] = A_c[row, :] @ W_c[:, n] + b_c[n]
__global__ __launch_bounds__(256) void gemm_fused_kernel(
    const short* __restrict__ A_arena, const short* __restrict__ Wt_arena,
    const float* __restrict__ b0, const float* __restrict__ b1,
    const float* __restrict__ b2, const float* __restrict__ b3,
    const int* __restrict__ lists, const int* __restrict__ counts,
    float* __restrict__ out) {
    __shared__ short lds_A[4096];  // [quad][128 rows][8]
    __shared__ short lds_B[4096];
    __shared__ int row_dst[128];

    const int c0 = counts[0], c1 = counts[1], c2 = counts[2], c3 = counts[3];
    const int t0 = (c0 + 127) >> 7, t1 = (c1 + 127) >> 7;
    const int t2 = (c2 + 127) >> 7, t3 = (c3 + 127) >> 7;
    const int x = blockIdx.x;
    int cat, mt, count;
    if (x < t0)                     { cat = 0; mt = x; count = c0; }
    else if (x < t0 + t1)           { cat = 1; mt = x - t0; count = c1; }
    else if (x < t0 + t1 + t2)      { cat = 2; mt = x - t0 - t1; count = c2; }
    else if (x < t0 + t1 + t2 + t3) { cat = 3; mt = x - t0 - t1 - t2; count = c3; }
    else return;

    const int K = KS[cat];
    const int kp_n = K >> 5;
    const short* Abase = A_arena + OFFA[cat] + (size_t)mt * kp_n * 4096;
    const int nt = blockIdx.y;
    const short* Bbase = Wt_arena + OFFB[cat] + (size_t)nt * kp_n * 4096;
    const float* bias = cat == 0 ? b0 : cat == 1 ? b1 : cat == 2 ? b2 : b3;
    const int m0 = mt << 7;
    const int valid = min(128, count - m0);

    const int t = threadIdx.x;
    if (t < 128)
        row_dst[t] = (t < valid) ? (lists[cat * TOKENS + m0 + t] & 32767) : -1;

    const int w = t >> 6, L = t & 63;
    const int quad = L >> 4, l16 = L & 15;
    const int m_off = (w & 1) * 64;
    const int n_off = (w >> 1) * 64;
    const int s0 = (w * 2) * 64 + L;      // slot for issue 0
    const int s1 = (w * 2 + 1) * 64 + L;  // slot for issue 1

    f32x4 acc[4][4];
#pragma unroll
    for (int i = 0; i < 4; ++i)
#pragma unroll
        for (int j = 0; j < 4; ++j) acc[i][j] = (f32x4)0.0f;

    __syncthreads();  // row_dst visible; also LDS reuse safety

    for (int kp = 0; kp < kp_n; ++kp) {
        const short* gA = Abase + (size_t)kp * 4096;
        const short* gB = Bbase + (size_t)kp * 4096;
        GLDS16(gA + (size_t)s0 * 8, &lds_A[(w * 2) * 512]);
        GLDS16(gA + (size_t)s1 * 8, &lds_A[(w * 2 + 1) * 512]);
        GLDS16(gB + (size_t)s0 * 8, &lds_B[(w * 2) * 512]);
        GLDS16(gB + (size_t)s1 * 8, &lds_B[(w * 2 + 1) * 512]);
        __syncthreads();

        short8 af[4], bf[4];
#pragma unroll
        for (int mi = 0; mi < 4; ++mi)
            af[mi] = *(const short8*)&lds_A[quad * 1024 +
                                            (m_off + mi * 16 + l16) * 8];
#pragma unroll
        for (int ni = 0; ni < 4; ++ni)
            bf[ni] = *(const short8*)&lds_B[quad * 1024 +
                                            (n_off + ni * 16 + l16) * 8];
#pragma unroll
        for (int mi = 0; mi < 4; ++mi)
#pragma unroll
            for (int ni = 0; ni < 4; ++ni)
                acc[mi][ni] = __builtin_amdgcn_mfma_f32_16x16x32_bf16(
                    af[mi], bf[ni], acc[mi][ni], 0, 0, 0);
        __syncthreads();
    }

    float bv[4];
#pragma unroll
    for (int ni = 0; ni < 4; ++ni)
        bv[ni] = bias[nt * 128 + n_off + ni * 16 + l16];

#pragma unroll
    for (int mi = 0; mi < 4; ++mi) {
        int mb = m_off + mi * 16 + quad * 4;
#pragma unroll
        for (int r = 0; r < 4; ++r) {
            int m = mb + r;
            if (m < valid) {
                size_t dst = (size_t)row_dst[m] * DOUT;
#pragma unroll
                for (int ni = 0; ni < 4; ++ni)
                    out[dst + nt * 128 + n_off + ni * 16 + l16] =
                        acc[mi][ni][r] + bv[ni];
            }
        }
    }
}

// ---- fallback GEMM (round-1, known-good; used only if ws too small) --------
__global__ __launch_bounds__(256) void gemm_direct_kernel(
    const float* __restrict__ emb, const float* __restrict__ W,
    const float* __restrict__ bias, const int* __restrict__ list,
    const int* __restrict__ count_p, float* __restrict__ out, int K) {
    __shared__ short lds_A[128 * 40];
    __shared__ short lds_B[128 * 40];
    __shared__ int row_tok[128];
    __shared__ int row_dst[128];

    const int count = *count_p;
    const int m0 = blockIdx.x * 128;
    if (m0 >= count) return;
    const int valid = min(128, count - m0);
    const int n0 = blockIdx.y * 128;
    const int t = threadIdx.x;
    if (t < 128) {
        if (t < valid) {
            unsigned pack = (unsigned)list[m0 + t];
            row_tok[t] = (int)(pack >> 15);
            row_dst[t] = (int)(pack & 32767u);
        } else { row_tok[t] = 0; row_dst[t] = -1; }
    }
    __syncthreads();

    const int w = t >> 6, L = t & 63;
    const int quad = L >> 4, l16 = L & 15;
    const int m_off = (w & 1) * 64, n_off = (w >> 1) * 64;
    f32x4 acc[4][4];
#pragma unroll
    for (int i = 0; i < 4; ++i)
#pragma unroll
        for (int j = 0; j < 4; ++j) acc[i][j] = (f32x4)0.0f;

    const int ar = t >> 1, acg = (t & 1) * 16;
    const size_t arow = (size_t)row_tok[ar] * (size_t)K;

    for (int k0 = 0; k0 < K; k0 += 32) {
        const float4* src = reinterpret_cast<const float4*>(emb + arow + k0 + acg);
        float4 f0 = src[0], f1 = src[1], f2 = src[2], f3 = src[3];
        short8 v0, v1;
        v0[0] = f2bf(f0.x); v0[1] = f2bf(f0.y); v0[2] = f2bf(f0.z); v0[3] = f2bf(f0.w);
        v0[4] = f2bf(f1.x); v0[5] = f2bf(f1.y); v0[6] = f2bf(f1.z); v0[7] = f2bf(f1.w);
        v1[0] = f2bf(f2.x); v1[1] = f2bf(f2.y); v1[2] = f2bf(f2.z); v1[3] = f2bf(f2.w);
        v1[4] = f2bf(f3.x); v1[5] = f2bf(f3.y); v1[6] = f2bf(f3.z); v1[7] = f2bf(f3.w);
        *(short8*)&lds_A[ar * 40 + acg] = v0;
        *(short8*)&lds_A[ar * 40 + acg + 8] = v1;
        const int bk = t >> 3, bq = (t & 7) * 4;
#pragma unroll
        for (int q = 0; q < 4; ++q) {
            int nb = bq + q * 32;
            float4 f = *reinterpret_cast<const float4*>(
                W + (size_t)(k0 + bk) * DOUT + n0 + nb);
            lds_B[(nb + 0) * 40 + bk] = f2bf(f.x);
            lds_B[(nb + 1) * 40 + bk] = f2bf(f.y);
            lds_B[(nb + 2) * 40 + bk] = f2bf(f.z);
            lds_B[(nb + 3) * 40 + bk] = f2bf(f.w);
        }
        __syncthreads();
        short8 af[4], bf[4];
#pragma unroll
        for (int mi = 0; mi < 4; ++mi)
            af[mi] = *(const short8*)&lds_A[(m_off + mi * 16 + l16) * 40 + quad * 8];
#pragma unroll
        for (int ni = 0; ni < 4; ++ni)
            bf[ni] = *(const short8*)&lds_B[(n_off + ni * 16 + l16) * 40 + quad * 8];
#pragma unroll
        for (int mi = 0; mi < 4; ++mi)
#pragma unroll
            for (int ni = 0; ni < 4; ++ni)
                acc[mi][ni] = __builtin_amdgcn_mfma_f32_16x16x32_bf16(
                    af[mi], bf[ni], acc[mi][ni], 0, 0, 0);
        __syncthreads();
    }
    float bv[4];
#pragma unroll
    for (int ni = 0; ni < 4; ++ni) bv[ni] = bias[n0 + n_off + ni * 16 + l16];
#pragma unroll
    for (int mi = 0; mi < 4; ++mi) {
        int mb = m_off + mi * 16 + quad * 4;
#pragma unroll
        for (int r = 0; r < 4; ++r) {
            int m = mb + r;
            if (m < valid) {
                size_t dst = (size_t)row_dst[m] * DOUT;
#pragma unroll
                for (int ni = 0; ni < 4; ++ni)
                    out[dst + n0 + n_off + ni * 16 + l16] = acc[mi][ni][r] + bv[ni];
            }
        }
    }
}

// ---------------------------------------------------------------------------
extern "C" void kernel_launch(void* const* d_in, const int* in_sizes, int n_in,
                              void* d_out, int out_size, void* d_ws, size_t ws_size,
                              hipStream_t stream) {
    const int* token_ids = (const int*)d_in[0];
    const int* cat_table = (const int*)d_in[1];
    const float* emb[4] = {(const float*)d_in[2], (const float*)d_in[5],
                           (const float*)d_in[8], (const float*)d_in[11]};
    const float* Wm[4]  = {(const float*)d_in[3], (const float*)d_in[6],
                           (const float*)d_in[9], (const float*)d_in[12]};
    const float* bm[4]  = {(const float*)d_in[4], (const float*)d_in[7],
                           (const float*)d_in[10], (const float*)d_in[13]};
    float* out = (float*)d_out;

    char* ws = (char*)d_ws;
    int* counts = (int*)ws;                        // 16 B
    int* lists = (int*)(ws + 16);                  // 4*32768*4 = 512 KB
    size_t off = (16 + (size_t)4 * TOKENS * 4 + 255) & ~(size_t)255;
    short* wt_arena = (short*)(ws + off);          // 1024*3328*2 = 6.8 MB
    off += (size_t)DOUT * 3328 * sizeof(short);
    off = (off + 255) & ~(size_t)255;
    short* a_arena = (short*)(ws + off);           // 32768*3328*2 = 218 MB
    off += (size_t)TOKENS * 3328 * sizeof(short);
    const bool fast = (ws_size >= off);

    hipMemsetAsync(counts, 0, 16, stream);
    compact_kernel<<<TOKENS / 256, 256, 0, stream>>>(token_ids, cat_table,
                                                     counts, lists);
    if (fast) {
        conv_w_kernel<<<dim3(104, 8), 256, 0, stream>>>(
            Wm[0], Wm[1], Wm[2], Wm[3], wt_arena);
        gather_a_kernel<<<dim3(64, 4), 256, 0, stream>>>(
            emb[0], emb[1], emb[2], emb[3], a_arena, lists, counts);
        gemm_fused_kernel<<<dim3(260, 8), 256, 0, stream>>>(
            a_arena, wt_arena, bm[0], bm[1], bm[2], bm[3], lists, counts, out);
    } else {
        dim3 grid(TOKENS / 128, DOUT / 128);
        for (int c = 0; c < 4; ++c) {
            const int Ks[4] = {1536, 1024, 512, 256};
            gemm_direct_kernel<<<grid, 256, 0, stream>>>(
                emb[c], Wm[c], bm[c], lists + c * TOKENS, counts + c, out, Ks[c]);
        }
    }
}